// Round 5
// baseline (323.547 us; speedup 1.0000x reference)
//
#include <hip/hip_runtime.h>
#include <hip/hip_bf16.h>
#include <hip/hip_cooperative_groups.h>
#include <stdint.h>

namespace cg = cooperative_groups;

#define Bn 4
#define Cn 64
#define Fn 50000
#define Kn 16
#define NTOT (Bn*Fn)
#define EPS 1e-5f

typedef unsigned short u16;
typedef unsigned int u32;
typedef __attribute__((ext_vector_type(8))) short short8;
typedef __attribute__((ext_vector_type(4))) float f32x4;
typedef __attribute__((ext_vector_type(2))) float f32x2;
typedef __attribute__((ext_vector_type(4))) int i32x4;
typedef __attribute__((ext_vector_type(4))) unsigned int u32x4;

__device__ __forceinline__ u16 f2bf(float x) {
  __hip_bfloat16 h = __float2bfloat16(x);
  return *reinterpret_cast<u16*>(&h);
}
__device__ __forceinline__ u32 pack2(float a, float b) {
  return (u32)f2bf(a) | ((u32)f2bf(b) << 16);
}
__device__ __forceinline__ f32x2 up2(u32 uu) {     // bf16 pair -> f32 pair
  f32x2 r;
  r.x = __uint_as_float(uu << 16);
  r.y = __uint_as_float(uu & 0xffff0000u);
  return r;
}

// ============================================================================
// MEGA (cooperative, 1 dispatch): GEMM -> sync -> gather+stats -> sync -> norm
// Every phase distributes work EXACTLY evenly over gridDim (round-3 lesson:
// strided leftovers under a grid barrier double the critical path).
// ============================================================================
__global__ __launch_bounds__(256) void mega(
    const float* __restrict__ fea, const int* __restrict__ ring,
    const float* __restrict__ W, const float* __restrict__ bias,
    u32* __restrict__ Gt, u32* __restrict__ Y, float* __restrict__ gsum,
    const float* __restrict__ gamma, const float* __restrict__ beta,
    float* __restrict__ out) {
  const int t = threadIdx.x;
  const int bid = blockIdx.x;
  const int G = (int)gridDim.x;
  const int l = t & 63;
  const int quad = l >> 4;
  const int lane15 = l & 15;
  const int wv = t >> 6;

  __shared__ union SM {
    float a_s[32][65];                                  //  8320 B (phase 0)
    struct { float rs[32][68]; float rs2[32][68]; } s;  // 17408 B (phase 1)
    u32 ys[32][17];                                     //  2176 B (phase 3)
  } sm;

  if (bid == 0 && t < 128) gsum[t] = 0.f;   // visible after grid.sync #1

  // ---- phase 0: Gt[b][face][64ch] bf16 = W x fea[b]; 64-face tiles,
  //      split-K (two 32-ch halves through an 8.3 KB LDS stage).
  {
    const int NT0 = 782 * Bn;               // ceil(50000/64) * B
    int v0 = (int)((long long)bid * NT0 / G);
    const int v0e = (int)((long long)(bid + 1) * NT0 / G);
    const int f4 = t & 15, cb = t >> 4;
    for (; v0 < v0e; v0++) {
      const int b = v0 / 782;
      const int fx = v0 - b * 782;
      const int f0 = fx * 64;
      const float* fb = fea + (size_t)b * Cn * Fn;
      f32x4 acc[4];
      #pragma unroll
      for (int ot = 0; ot < 4; ot++) acc[ot] = (f32x4){0.f, 0.f, 0.f, 0.f};
      #pragma unroll
      for (int h = 0; h < 2; h++) {
        // stage 32 ch x 64 faces fp32 (coalesced 256 B runs per 16 lanes)
        const bool fvalid = (f0 + f4 * 4) < Fn;   // Fn%4==0
        #pragma unroll
        for (int jj = 0; jj < 2; jj++) {
          int c = cb + jj * 16;
          float4 v = make_float4(0.f, 0.f, 0.f, 0.f);
          if (fvalid) v = *(const float4*)(fb + (size_t)(h * 32 + c) * Fn + f0 + f4 * 4);
          *(float4*)&sm.a_s[c][f4 * 4] = v;
        }
        __syncthreads();
        // A-frags for this k-half (W hot in L1/L2)
        short8 af[4];
        #pragma unroll
        for (int ot = 0; ot < 4; ot++) {
          const float* wr = W + (ot * 16 + lane15) * 64 + h * 32 + quad * 8;
          float4 wa = *(const float4*)wr;
          float4 wb = *(const float4*)(wr + 4);
          union { short8 v; u32 u[4]; } fr;
          fr.u[0] = pack2(wa.x, wa.y); fr.u[1] = pack2(wa.z, wa.w);
          fr.u[2] = pack2(wb.x, wb.y); fr.u[3] = pack2(wb.z, wb.w);
          af[ot] = fr.v;
        }
        // B-frag: k = quad*8+j, n = face = wv*16+lane15
        const int fl = wv * 16 + lane15;
        float x[8];
        #pragma unroll
        for (int j = 0; j < 8; j++) x[j] = sm.a_s[quad * 8 + j][fl];
        union { short8 s; u32 u[4]; } b0;
        #pragma unroll
        for (int p = 0; p < 4; p++) b0.u[p] = pack2(x[2 * p], x[2 * p + 1]);
        #pragma unroll
        for (int ot = 0; ot < 4; ot++)
          acc[ot] = __builtin_amdgcn_mfma_f32_16x16x32_bf16(af[ot], b0.s, acc[ot], 0, 0, 0);
        __syncthreads();     // a_s free for restage / next tile
      }
      // D store: row o = ot*16+quad*4+r, col f = lane15 -> uint2 per ot
      const int fg = f0 + wv * 16 + lane15;
      if (fg < Fn) {
        #pragma unroll
        for (int ot = 0; ot < 4; ot++) {
          uint2 pv;
          pv.x = pack2(acc[ot][0], acc[ot][1]);
          pv.y = pack2(acc[ot][2], acc[ot][3]);
          *(uint2*)(Gt + ((size_t)b * Fn + fg) * 32 + ot * 8 + quad * 2) = pv;
        }
      }
    }
  }

  cg::this_grid().sync();

  // ---- phase 1: gather + bias + stats. b pinned per XCD-pair (bid&7),
  //      contiguous face range per block (imbalance <= 1 face).
  {
    const int Gb = G >> 2;                           // blocks per batch
    const int b = (bid & 7) >> 1;
    const int sub = ((bid >> 3) << 1) | (bid & 1);   // [0, Gb)
    const int gid = t >> 3, cs = t & 7;
    const u32* Gbp = Gt + (size_t)b * Fn * 32;
    const int* rb = ring + (size_t)b * Fn * Kn;
    const int f_begin = (int)((long long)sub * Fn / Gb);
    const int f_end   = (int)((long long)(sub + 1) * Fn / Gb);
    const int nt = (f_end - f_begin + 31) >> 5;

    f32x2 bv2[4];
    #pragma unroll
    for (int p = 0; p < 4; p++) {
      bv2[p].x = bias[cs * 8 + 2 * p];
      bv2[p].y = bias[cs * 8 + 2 * p + 1];
    }
    f32x2 sacc2[4], s2acc2[4];
    #pragma unroll
    for (int p = 0; p < 4; p++) { sacc2[p] = (f32x2)(0.f); s2acc2[p] = (f32x2)(0.f); }

    i32x4 r0, r1, r2, r3;
    {
      int fa = f_begin + gid;
      int fc = fa < f_end ? fa : f_begin;
      const i32x4* rp = (const i32x4*)(rb + (size_t)fc * Kn);
      r0 = __builtin_nontemporal_load(&rp[0]);
      r1 = __builtin_nontemporal_load(&rp[1]);
      r2 = __builtin_nontemporal_load(&rp[2]);
      r3 = __builtin_nontemporal_load(&rp[3]);
    }

    for (int it = 0; it < nt; it++) {
      const int fa = f_begin + it * 32 + gid;
      const bool valid = fa < f_end;
      int idx[16] = {r0[0],r0[1],r0[2],r0[3], r1[0],r1[1],r1[2],r1[3],
                     r2[0],r2[1],r2[2],r2[3], r3[0],r3[1],r3[2],r3[3]};
      if (it + 1 < nt) {                    // prefetch next tile's indices
        int nfa = f_begin + (it + 1) * 32 + gid;
        int nfc = nfa < f_end ? nfa : f_begin;
        const i32x4* rp = (const i32x4*)(rb + (size_t)nfc * Kn);
        r0 = __builtin_nontemporal_load(&rp[0]);
        r1 = __builtin_nontemporal_load(&rp[1]);
        r2 = __builtin_nontemporal_load(&rp[2]);
        r3 = __builtin_nontemporal_load(&rp[3]);
      }

      f32x2 acc2[4];
      #pragma unroll
      for (int p = 0; p < 4; p++) acc2[p] = bv2[p];

      u32x4 v[8];
      #pragma unroll
      for (int k = 0; k < 8; k++)
        v[k] = *(const u32x4*)(Gbp + (size_t)idx[k] * 32 + cs * 4);
      #pragma unroll
      for (int k = 0; k < 8; k++) {
        #pragma unroll
        for (int p = 0; p < 4; p++) acc2[p] += up2(v[k][p]);
      }
      #pragma unroll
      for (int k = 0; k < 8; k++)
        v[k] = *(const u32x4*)(Gbp + (size_t)idx[8 + k] * 32 + cs * 4);
      #pragma unroll
      for (int k = 0; k < 8; k++) {
        #pragma unroll
        for (int p = 0; p < 4; p++) acc2[p] += up2(v[k][p]);
      }

      if (valid) {
        u32x4 pv;
        pv[0] = pack2(acc2[0].x, acc2[0].y); pv[1] = pack2(acc2[1].x, acc2[1].y);
        pv[2] = pack2(acc2[2].x, acc2[2].y); pv[3] = pack2(acc2[3].x, acc2[3].y);
        __builtin_nontemporal_store(pv,            // don't thrash L2 (R3 lesson)
            (u32x4*)(Y + ((size_t)b * Fn + fa) * 32 + cs * 4));
        #pragma unroll
        for (int p = 0; p < 4; p++) {
          sacc2[p] += acc2[p];
          s2acc2[p] += acc2[p] * acc2[p];
        }
      }
    }

    // block stats reduce + one atomic round
    __syncthreads();                                // sm ownership
    #pragma unroll
    for (int p = 0; p < 4; p++) {
      sm.s.rs[gid][cs * 8 + 2 * p] = sacc2[p].x;
      sm.s.rs[gid][cs * 8 + 2 * p + 1] = sacc2[p].y;
      sm.s.rs2[gid][cs * 8 + 2 * p] = s2acc2[p].x;
      sm.s.rs2[gid][cs * 8 + 2 * p + 1] = s2acc2[p].y;
    }
    __syncthreads();
    if (t < 64) {
      float s = 0.f;
      #pragma unroll
      for (int g = 0; g < 32; g++) s += sm.s.rs[g][t];
      atomicAdd(&gsum[t], s);
    } else if (t < 128) {
      const int ch = t - 64;
      float s2 = 0.f;
      #pragma unroll
      for (int g = 0; g < 32; g++) s2 += sm.s.rs2[g][ch];
      atomicAdd(&gsum[64 + ch], s2);
    }
  }

  cg::this_grid().sync();

  // ---- phase 3: BN normalize + relu; 16-face tiles (50000 = 3125*16 exact)
  {
    const int NT3 = 3125 * Bn;
    int v3 = (int)((long long)bid * NT3 / G);
    const int v3e = (int)((long long)(bid + 1) * NT3 / G);
    const int ch = t >> 2, fg3 = t & 3;
    const float inv = 1.0f / (float)NTOT;
    const float mean = gsum[ch] * inv;
    const float var = gsum[64 + ch] * inv - mean * mean;   // biased
    const float a_ = gamma[ch] * rsqrtf(var + EPS);
    const float c_ = beta[ch] - mean * a_;
    const int c2 = ch >> 1;
    const bool hi = ch & 1;
    for (; v3 < v3e; v3++) {
      const int b = v3 / 3125;
      const int tx = v3 - b * 3125;
      const int fa0 = tx * 16;
      __syncthreads();                       // sm.ys reuse guard
      if (t < 128) {
        const int fl = t >> 3, sl = (t & 7) * 4;
        u32x4 vv = __builtin_nontemporal_load(
            (const u32x4*)(Y + ((size_t)b * Fn + fa0 + fl) * 32 + sl));
        sm.ys[sl + 0][fl] = vv[0]; sm.ys[sl + 1][fl] = vv[1];
        sm.ys[sl + 2][fl] = vv[2]; sm.ys[sl + 3][fl] = vv[3];
      }
      __syncthreads();
      f32x4 res;
      #pragma unroll
      for (int rr = 0; rr < 4; rr++) {
        u32 u = sm.ys[c2][fg3 * 4 + rr];
        float xv = __uint_as_float(hi ? (u & 0xffff0000u) : (u << 16));
        res[rr] = fmaxf(fmaf(xv, a_, c_), 0.f);
      }
      __builtin_nontemporal_store(res,
          (f32x4*)(out + ((size_t)b * 64 + ch) * Fn + fa0 + fg3 * 4));
    }
  }
}

// ============================================================================
// Fallback path (proven round-2 kernels, 3 dispatches; k1 zeroes gsum)
// ============================================================================
__global__ __launch_bounds__(256) void k1_mfma(
    const float* __restrict__ fea, const float* __restrict__ W,
    u32* __restrict__ Gt, float* __restrict__ gsum) {
  const int b = blockIdx.y;
  const int f0 = blockIdx.x * 128;
  const int t = threadIdx.x;
  const int l = t & 63;
  const int quad = l >> 4;
  const int lane15 = l & 15;
  const int wv = t >> 6;
  __shared__ float a_s[64][129];

  if (blockIdx.x == 0 && b == 0 && t < 128) gsum[t] = 0.f;

  short8 afr[4][2];
  #pragma unroll
  for (int ot = 0; ot < 4; ot++) {
    #pragma unroll
    for (int kk = 0; kk < 2; kk++) {
      const float* wr = W + (ot * 16 + lane15) * 64 + kk * 32 + quad * 8;
      float4 wa = *(const float4*)wr;
      float4 wb = *(const float4*)(wr + 4);
      union { short8 v; u32 u[4]; } fr;
      fr.u[0] = pack2(wa.x, wa.y); fr.u[1] = pack2(wa.z, wa.w);
      fr.u[2] = pack2(wb.x, wb.y); fr.u[3] = pack2(wb.z, wb.w);
      afr[ot][kk] = fr.v;
    }
  }
  {
    const float* fb = fea + (size_t)b * Cn * Fn;
    const int f4 = t & 31;
    const int cbase = t >> 5;
    const bool fvalid = (f0 + f4 * 4) < Fn;
    #pragma unroll
    for (int jj = 0; jj < 8; jj++) {
      int c = cbase + jj * 8;
      float4 v = make_float4(0.f, 0.f, 0.f, 0.f);
      if (fvalid) v = *(const float4*)(fb + (size_t)c * Fn + f0 + f4 * 4);
      *(float4*)&a_s[c][f4 * 4] = v;
    }
  }
  __syncthreads();

  f32x4 acc[4][2];
  #pragma unroll
  for (int ot = 0; ot < 4; ot++)
    #pragma unroll
    for (int ft = 0; ft < 2; ft++) acc[ot][ft] = (f32x4){0.f, 0.f, 0.f, 0.f};

  #pragma unroll
  for (int ft = 0; ft < 2; ft++) {
    const int fl = wv * 32 + ft * 16 + lane15;
    float x[16];
    #pragma unroll
    for (int j = 0; j < 8; j++) x[j] = a_s[quad * 8 + j][fl];
    #pragma unroll
    for (int j = 0; j < 8; j++) x[8 + j] = a_s[32 + quad * 8 + j][fl];
    union { short8 s; u32 u[4]; } b0, b1;
    #pragma unroll
    for (int p = 0; p < 4; p++) {
      b0.u[p] = pack2(x[2 * p], x[2 * p + 1]);
      b1.u[p] = pack2(x[8 + 2 * p], x[8 + 2 * p + 1]);
    }
    #pragma unroll
    for (int ot = 0; ot < 4; ot++) {
      acc[ot][ft] = __builtin_amdgcn_mfma_f32_16x16x32_bf16(afr[ot][0], b0.s, acc[ot][ft], 0, 0, 0);
      acc[ot][ft] = __builtin_amdgcn_mfma_f32_16x16x32_bf16(afr[ot][1], b1.s, acc[ot][ft], 0, 0, 0);
    }
  }

  __syncthreads();
  u32* ts = (u32*)&a_s[0][0];
  #pragma unroll
  for (int ot = 0; ot < 4; ot++) {
    #pragma unroll
    for (int ft = 0; ft < 2; ft++) {
      int fl = wv * 32 + ft * 16 + lane15;
      uint2 pv;
      pv.x = pack2(acc[ot][ft][0], acc[ot][ft][1]);
      pv.y = pack2(acc[ot][ft][2], acc[ot][ft][3]);
      *(uint2*)&ts[fl * 36 + ot * 8 + quad * 2] = pv;
    }
  }
  __syncthreads();
  #pragma unroll
  for (int j = 0; j < 4; j++) {
    int o = j * 1024 + t * 4;
    int fl = o >> 5, sl = o & 31;
    if (f0 + fl < Fn) {
      u32x4 vv = *(const u32x4*)&ts[fl * 36 + sl];
      *(u32x4*)(Gt + ((size_t)b * Fn + f0 + fl) * 32 + sl) = vv;
    }
  }
}

template<int WRITE_BF16>
__global__ __launch_bounds__(256) void k2_gather(
    const u32* __restrict__ Gt, const int* __restrict__ ring,
    const float* __restrict__ bias, u32* __restrict__ Y, float* __restrict__ outF,
    float* __restrict__ gsum, float* __restrict__ gsum2) {
  const int bid = blockIdx.x;
  const int b = (bid & 7) >> 1;
  const int sub = ((bid >> 3) << 1) | (bid & 1);
  const int t = threadIdx.x;
  const int gid = t >> 3;
  const int cs = t & 7;

  __shared__ float rs[32][68];
  __shared__ float rs2[32][68];

  float bv[8];
  #pragma unroll
  for (int i = 0; i < 8; i++) bv[i] = bias[cs * 8 + i];

  const u32* Gb = Gt + (size_t)b * Fn * 32;
  const int* rb = ring + (size_t)b * Fn * Kn;

  float sacc[8], s2acc[8];
  #pragma unroll
  for (int i = 0; i < 8; i++) { sacc[i] = 0.f; s2acc[i] = 0.f; }

  const int ntiles = (Fn + 31) / 32;

  int tile = sub;
  i32x4 r0, r1, r2, r3;
  if (tile < ntiles) {
    int fa = tile * 32 + gid;
    int fc = fa < Fn ? fa : Fn - 1;
    const i32x4* rp = (const i32x4*)(rb + (size_t)fc * Kn);
    r0 = __builtin_nontemporal_load(&rp[0]);
    r1 = __builtin_nontemporal_load(&rp[1]);
    r2 = __builtin_nontemporal_load(&rp[2]);
    r3 = __builtin_nontemporal_load(&rp[3]);
  }

  for (; tile < ntiles; tile += 512) {
    const int fa = tile * 32 + gid;
    const bool valid = fa < Fn;
    int idx[16] = {r0[0],r0[1],r0[2],r0[3], r1[0],r1[1],r1[2],r1[3],
                   r2[0],r2[1],r2[2],r2[3], r3[0],r3[1],r3[2],r3[3]};

    const int ntile = tile + 512;
    if (ntile < ntiles) {
      int nfa = ntile * 32 + gid;
      int nfc = nfa < Fn ? nfa : Fn - 1;
      const i32x4* rp = (const i32x4*)(rb + (size_t)nfc * Kn);
      r0 = __builtin_nontemporal_load(&rp[0]);
      r1 = __builtin_nontemporal_load(&rp[1]);
      r2 = __builtin_nontemporal_load(&rp[2]);
      r3 = __builtin_nontemporal_load(&rp[3]);
    }

    float acc[8];
    #pragma unroll
    for (int i = 0; i < 8; i++) acc[i] = 0.f;

    u32x4 v[8];
    #pragma unroll
    for (int k = 0; k < 8; k++)
      v[k] = *(const u32x4*)(Gb + (size_t)idx[k] * 32 + cs * 4);
    #pragma unroll
    for (int k = 0; k < 8; k++) {
      #pragma unroll
      for (int p = 0; p < 4; p++) {
        u32 uu = v[k][p];
        acc[2*p]   += __uint_as_float(uu << 16);
        acc[2*p+1] += __uint_as_float(uu & 0xffff0000u);
      }
    }
    #pragma unroll
    for (int k = 0; k < 8; k++)
      v[k] = *(const u32x4*)(Gb + (size_t)idx[8 + k] * 32 + cs * 4);
    #pragma unroll
    for (int k = 0; k < 8; k++) {
      #pragma unroll
      for (int p = 0; p < 4; p++) {
        u32 uu = v[k][p];
        acc[2*p]   += __uint_as_float(uu << 16);
        acc[2*p+1] += __uint_as_float(uu & 0xffff0000u);
      }
    }

    float yv[8];
    #pragma unroll
    for (int i = 0; i < 8; i++) yv[i] = acc[i] + bv[i];

    if (valid) {
      if (WRITE_BF16) {
        u32x4 pv;
        pv[0] = pack2(yv[0], yv[1]); pv[1] = pack2(yv[2], yv[3]);
        pv[2] = pack2(yv[4], yv[5]); pv[3] = pack2(yv[6], yv[7]);
        __builtin_nontemporal_store(pv,
            (u32x4*)(Y + ((size_t)b * Fn + fa) * 32 + cs * 4));
      } else {
        #pragma unroll
        for (int i = 0; i < 8; i++)
          outF[((size_t)b * 64 + cs * 8 + i) * Fn + fa] = yv[i];
      }
      #pragma unroll
      for (int i = 0; i < 8; i++) {
        sacc[i] += yv[i];
        s2acc[i] += yv[i] * yv[i];
      }
    }
  }

  #pragma unroll
  for (int i = 0; i < 8; i++) {
    rs[gid][cs * 8 + i] = sacc[i];
    rs2[gid][cs * 8 + i] = s2acc[i];
  }
  __syncthreads();
  if (t < 64) {
    float s = 0.f;
    #pragma unroll
    for (int g = 0; g < 32; g++) s += rs[g][t];
    atomicAdd(&gsum[t], s);
  } else if (t < 128) {
    const int ch = t - 64;
    float s2 = 0.f;
    #pragma unroll
    for (int g = 0; g < 32; g++) s2 += rs2[g][ch];
    atomicAdd(&gsum2[ch], s2);
  }
}

__global__ void k3_stats(const float* __restrict__ gsum, const float* __restrict__ gsum2,
                         const float* __restrict__ gamma, const float* __restrict__ beta,
                         float* __restrict__ ab) {
  int o = threadIdx.x;
  if (o < 64) {
    float inv = 1.0f / (float)NTOT;
    float mean = gsum[o] * inv;
    float var = gsum2[o] * inv - mean * mean;
    float r = rsqrtf(var + EPS);
    float a = gamma[o] * r;
    ab[o] = a;
    ab[64 + o] = beta[o] - mean * a;
  }
}

__global__ __launch_bounds__(256) void k4_norm_bf(
    const u32* __restrict__ Y, const float* __restrict__ gsum,
    const float* __restrict__ gsum2, const float* __restrict__ gamma,
    const float* __restrict__ beta, float* __restrict__ out) {
  const int b = blockIdx.y;
  const int f0 = blockIdx.x * 64;
  const int t = threadIdx.x;
  __shared__ u32 ys[32][65];

  #pragma unroll
  for (int j = 0; j < 2; j++) {
    int o = j * 1024 + t * 4;
    int fl = o >> 5, sl = o & 31;
    u32x4 vv = (u32x4)(0u);
    if (f0 + fl < Fn)
      vv = *(const u32x4*)(Y + ((size_t)b * Fn + f0 + fl) * 32 + sl);
    ys[sl + 0][fl] = vv[0]; ys[sl + 1][fl] = vv[1];
    ys[sl + 2][fl] = vv[2]; ys[sl + 3][fl] = vv[3];
  }
  __syncthreads();

  const float inv = 1.0f / (float)NTOT;
  const int fi = t & 15, g = t >> 4;
  const int fbase = 4 * fi;
  #pragma unroll
  for (int j = 0; j < 4; j++) {
    int ch = g * 4 + j;
    float mean = gsum[ch] * inv;
    float var = gsum2[ch] * inv - mean * mean;
    float a = gamma[ch] * rsqrtf(var + EPS);
    float cc = beta[ch] - mean * a;
    if (f0 + fbase < Fn) {
      const int c2 = ch >> 1;
      const bool hi = ch & 1;
      float r[4];
      #pragma unroll
      for (int rr = 0; rr < 4; rr++) {
        u32 u = ys[c2][fbase + rr];
        float xv = __uint_as_float(hi ? (u & 0xffff0000u) : (u << 16));
        r[rr] = fmaxf(fmaf(xv, a, cc), 0.f);
      }
      float4 res = make_float4(r[0], r[1], r[2], r[3]);
      *(float4*)(out + ((size_t)b * 64 + ch) * Fn + f0 + fbase) = res;
    }
  }
}

__global__ __launch_bounds__(256) void k4_norm_f32(float* __restrict__ out,
                                                   const float* __restrict__ ab) {
  int i = blockIdx.x * 256 + threadIdx.x;
  int o = (i / (Fn / 4)) & 63;
  float a = ab[o], c = ab[64 + o];
  float4 v = ((float4*)out)[i];
  v.x = fmaxf(fmaf(v.x, a, c), 0.f);
  v.y = fmaxf(fmaf(v.y, a, c), 0.f);
  v.z = fmaxf(fmaf(v.z, a, c), 0.f);
  v.w = fmaxf(fmaf(v.w, a, c), 0.f);
  ((float4*)out)[i] = v;
}

extern "C" void kernel_launch(void* const* d_in, const int* in_sizes, int n_in,
                              void* d_out, int out_size, void* d_ws, size_t ws_size,
                              hipStream_t stream) {
  const float* fea   = (const float*)d_in[0];
  const int*   ring  = (const int*)d_in[1];
  const float* W     = (const float*)d_in[2];
  const float* bias  = (const float*)d_in[3];
  const float* gamma = (const float*)d_in[4];
  const float* beta  = (const float*)d_in[5];
  float* out = (float*)d_out;

  u32* Gt = (u32*)d_ws;                                   // [B][Fn][32 u32] = 25.6 MB
  const size_t gtBytes = (size_t)Bn * Fn * 32 * 4;
  const size_t yBytes  = (size_t)Bn * Fn * 32 * 4;        // 25.6 MB
  const bool bf16y = ws_size >= gtBytes + yBytes + 1024;

  u32* Y = Gt + (size_t)Bn * Fn * 32;
  float* gsum  = bf16y ? (float*)((char*)d_ws + gtBytes + yBytes)
                       : (float*)((char*)d_ws + gtBytes);
  float* gsum2 = gsum + 64;
  float* ab    = gsum + 128;

  // cached occupancy query (host-side, once per process)
  static int mega_nb = -2;
  if (mega_nb == -2) {
    int nb = 0;
    mega_nb = (hipOccupancyMaxActiveBlocksPerMultiprocessor(&nb, mega, 256, 0)
               == hipSuccess && nb > 0) ? nb : -1;
  }

  bool done = false;
  if (bf16y && mega_nb > 0) {
    int G = mega_nb * 256;                 // 256 CUs
    if (G > 2048) G = 2048;
    G &= ~7;                               // phase-1 b-pinning needs G%8==0
    if (G >= 8) {
      void* args[] = {(void*)&fea, (void*)&ring, (void*)&W, (void*)&bias,
                      (void*)&Gt, (void*)&Y, (void*)&gsum,
                      (void*)&gamma, (void*)&beta, (void*)&out};
      hipError_t le = hipLaunchCooperativeKernel((const void*)mega, dim3(G),
                                                 dim3(256), args, 0, stream);
      done = (le == hipSuccess);
    }
  }
  if (!done) {   // proven 3-dispatch fallback (k1 zeroes gsum)
    k1_mfma<<<dim3((Fn + 127) / 128, Bn), 256, 0, stream>>>(fea, W, Gt, gsum);
    if (bf16y) {
      k2_gather<1><<<dim3(2048), 256, 0, stream>>>(Gt, ring, bias, Y, out, gsum, gsum2);
      k4_norm_bf<<<dim3((Fn + 63) / 64, Bn), 256, 0, stream>>>(Y, gsum, gsum2, gamma, beta, out);
    } else {
      k2_gather<0><<<dim3(2048), 256, 0, stream>>>(Gt, ring, bias, Y, out, gsum, gsum2);
      k3_stats<<<1, 64, 0, stream>>>(gsum, gsum2, gamma, beta, ab);
      k4_norm_f32<<<dim3((Bn * Cn * Fn / 4) / 256), 256, 0, stream>>>(out, ab);
    }
  }
}

// Round 6
// 204.508 us; speedup vs baseline: 1.5821x; 1.5821x over previous
//
#include <hip/hip_runtime.h>
#include <hip/hip_bf16.h>
#include <stdint.h>

#define Bn 4
#define Cn 64
#define Fn 50000
#define Kn 16
#define NTOT (Bn*Fn)
#define EPS 1e-5f

typedef unsigned short u16;
typedef unsigned int u32;
typedef __attribute__((ext_vector_type(8))) short short8;
typedef __attribute__((ext_vector_type(4))) float f32x4;
typedef __attribute__((ext_vector_type(2))) unsigned int u32x2;
typedef __attribute__((ext_vector_type(4))) int i32x4;
typedef __attribute__((ext_vector_type(4))) unsigned int u32x4;

__device__ __forceinline__ u16 f2bf(float x) {
  __hip_bfloat16 h = __float2bfloat16(x);
  return *reinterpret_cast<u16*>(&h);
}
__device__ __forceinline__ u32 pack2(float a, float b) {
  return (u32)f2bf(a) | ((u32)f2bf(b) << 16);
}
// async global->LDS, 16 B/lane; LDS dest = wave-uniform base + lane*16
__device__ __forceinline__ void gload_lds16(const float* g, float* l) {
  __builtin_amdgcn_global_load_lds(
      (const __attribute__((address_space(1))) u32*)(g),
      (__attribute__((address_space(3))) u32*)(l), 16, 0, 0);
}

// K1 (MFMA): Gt[(b*4+seg)][face][16ch] bf16 (32 B rows) = W x fea[b].
// 128-f tile. fea staged via global_load_lds width=16 (async DMA, no VGPR
// round-trip) into linear LDS [64ch][128f] fp32; the SOURCE face-block is
// pre-swizzled by channel-octet (fblk ^= (ch>>3)&3 << 1) so frag reads
// (fixed face, varying ch) land 2-way-per-bank = free (m136/m173).
// MFMA layouts (m89-verified): A[m=lane15][k=quad*8+j], B[k][n=lane15],
// D row=quad*4+r col=lane15. Epilogue: direct uint2 stores, 512 B/instr.
// Also zeroes gsum (block 0,0) -> no separate memset dispatch.
__global__ __launch_bounds__(256) void k1_mfma(
    const float* __restrict__ fea, const float* __restrict__ W,
    u32* __restrict__ Gt, float* __restrict__ gsum) {
  const int b = blockIdx.y;
  const int f0 = blockIdx.x * 128;
  const int t = threadIdx.x;
  const int l = t & 63;
  const int quad = l >> 4;
  const int lane15 = l & 15;
  const int wv = t >> 6;
  __shared__ float a_s[64 * 128];   // 32 KB linear -> 5 blocks/CU

  if (blockIdx.x == 0 && b == 0 && t < 128) gsum[t] = 0.f;

  // Stage first (async DMA overlaps the A-frag build below).
  // Wave w stages channels 16w..16w+15: 8 issues x (2 ch: lane<32 / lane>=32).
  {
    const float* fb = fea + (size_t)b * Cn * Fn;
    #pragma unroll
    for (int i = 0; i < 8; i++) {
      const int ch = wv * 16 + 2 * i + (l >> 5);
      const int fblk = (l & 31) ^ ((((ch >> 3) & 3)) << 1);  // pre-swizzled src
      int fg = f0 + fblk * 4;
      if (fg >= Fn) fg = f0;        // clamp: garbage faces never consumed
      gload_lds16(fb + (size_t)ch * Fn + fg, &a_s[(wv * 16 + 2 * i) * 128]);
    }
  }

  // A-frags: o = ot*16 + lane15, c = kk*32 + quad*8 + j  (W 64x64, cache-hot)
  short8 afr[4][2];
  #pragma unroll
  for (int ot = 0; ot < 4; ot++) {
    #pragma unroll
    for (int kk = 0; kk < 2; kk++) {
      const float* wr = W + (ot * 16 + lane15) * 64 + kk * 32 + quad * 8;
      float4 wa = *(const float4*)wr;
      float4 wb = *(const float4*)(wr + 4);
      union { short8 v; u32 u[4]; } fr;
      fr.u[0] = pack2(wa.x, wa.y); fr.u[1] = pack2(wa.z, wa.w);
      fr.u[2] = pack2(wb.x, wb.y); fr.u[3] = pack2(wb.z, wb.w);
      afr[ot][kk] = fr.v;
    }
  }
  __syncthreads();   // drains the global_load_lds queue (vmcnt0 before barrier)

  f32x4 acc[4][2];
  #pragma unroll
  for (int ot = 0; ot < 4; ot++)
    #pragma unroll
    for (int ft = 0; ft < 2; ft++) acc[ot][ft] = (f32x4){0.f, 0.f, 0.f, 0.f};

  #pragma unroll
  for (int ft = 0; ft < 2; ft++) {
    const int fl = wv * 32 + ft * 16 + lane15;
    const int fsw = fl ^ (quad << 3);       // read-side swizzle: ch-octet = quad
    float x[16];
    #pragma unroll
    for (int j = 0; j < 8; j++) x[j] = a_s[(quad * 8 + j) * 128 + fsw];
    #pragma unroll
    for (int j = 0; j < 8; j++) x[8 + j] = a_s[(32 + quad * 8 + j) * 128 + fsw];
    union { short8 s; u32 u[4]; } b0, b1;
    #pragma unroll
    for (int p = 0; p < 4; p++) {
      b0.u[p] = pack2(x[2 * p], x[2 * p + 1]);
      b1.u[p] = pack2(x[8 + 2 * p], x[8 + 2 * p + 1]);
    }
    #pragma unroll
    for (int ot = 0; ot < 4; ot++) {
      acc[ot][ft] = __builtin_amdgcn_mfma_f32_16x16x32_bf16(afr[ot][0], b0.s, acc[ot][ft], 0, 0, 0);
      acc[ot][ft] = __builtin_amdgcn_mfma_f32_16x16x32_bf16(afr[ot][1], b1.s, acc[ot][ft], 0, 0, 0);
    }
  }

  // Epilogue: o = ot*16 + quad*4 + r -> seg = ot; uint2 at u32-offset quad*2.
  // Per (ot,ft) instruction: 64 lanes cover 16 faces x 32 B = 512 B contiguous.
  #pragma unroll
  for (int ot = 0; ot < 4; ot++) {
    #pragma unroll
    for (int ft = 0; ft < 2; ft++) {
      int fg = f0 + wv * 32 + ft * 16 + lane15;
      if (fg < Fn) {
        uint2 pv;
        pv.x = pack2(acc[ot][ft][0], acc[ot][ft][1]);
        pv.y = pack2(acc[ot][ft][2], acc[ot][ft][3]);
        *(uint2*)(Gt + ((size_t)(b * 4 + ot) * Fn + fg) * 8 + quad * 2) = pv;
      }
    }
  }
}

// K2: unchanged round-0 structure (best measured with this layout: 67 us).
// block = (b,seg) x 128 faces, 32 B rows, 2 lanes/row. NT on ring + Y only.
template<int WRITE_BF16>
__global__ __launch_bounds__(256) void k2_gather(
    const u32* __restrict__ Gt, const int* __restrict__ ring,
    const float* __restrict__ bias, u32* __restrict__ Y, float* __restrict__ outF,
    float* __restrict__ gsum, float* __restrict__ gsum2) {
  const int bid = blockIdx.x;
  const int combo = bid & 15;
  const int ft = bid >> 4;
  const int b = combo >> 2;
  const int seg = combo & 3;
  const int t = threadIdx.x;
  const int face_l = t >> 1;          // 0..127
  const int half = t & 1;
  const int fa = ft * 128 + face_l;
  const bool valid = fa < Fn;

  __shared__ float y_s[128][17];
  __shared__ float rs[16][17];
  __shared__ float rs2[16][17];

  float acc[8];
  #pragma unroll
  for (int i = 0; i < 8; i++) acc[i] = 0.f;

  const int c0 = seg * 16 + half * 8;
  float bv[8];
  #pragma unroll
  for (int i = 0; i < 8; i++) bv[i] = bias[c0 + i];

  if (valid) {
    const i32x4* rp = (const i32x4*)(ring + ((size_t)b * Fn + fa) * Kn);
    i32x4 i0 = __builtin_nontemporal_load(&rp[0]);
    i32x4 i1 = __builtin_nontemporal_load(&rp[1]);
    i32x4 i2 = __builtin_nontemporal_load(&rp[2]);
    i32x4 i3 = __builtin_nontemporal_load(&rp[3]);
    int idx[16] = {i0[0],i0[1],i0[2],i0[3], i1[0],i1[1],i1[2],i1[3],
                   i2[0],i2[1],i2[2],i2[3], i3[0],i3[1],i3[2],i3[3]};
    const uint4* Gs = (const uint4*)(Gt + (size_t)combo * Fn * 8);
    uint4 v[8], w[8];
    #pragma unroll
    for (int k = 0; k < 8; k++) v[k] = Gs[(size_t)idx[k] * 2 + half];
    #pragma unroll
    for (int k = 0; k < 8; k++) w[k] = Gs[(size_t)idx[8 + k] * 2 + half];
    #pragma unroll
    for (int k = 0; k < 8; k++) {
      u32 uu[4] = {v[k].x, v[k].y, v[k].z, v[k].w};
      #pragma unroll
      for (int p = 0; p < 4; p++) {
        acc[2*p]   += __uint_as_float(uu[p] << 16);
        acc[2*p+1] += __uint_as_float(uu[p] & 0xffff0000u);
      }
    }
    #pragma unroll
    for (int k = 0; k < 8; k++) {
      u32 uu[4] = {w[k].x, w[k].y, w[k].z, w[k].w};
      #pragma unroll
      for (int p = 0; p < 4; p++) {
        acc[2*p]   += __uint_as_float(uu[p] << 16);
        acc[2*p+1] += __uint_as_float(uu[p] & 0xffff0000u);
      }
    }
  }
  #pragma unroll
  for (int i = 0; i < 8; i++) acc[i] = valid ? acc[i] + bv[i] : 0.f;
  #pragma unroll
  for (int i = 0; i < 8; i++) y_s[face_l][half * 8 + i] = acc[i];
  __syncthreads();

  if (WRITE_BF16) {
    const int fp = t & 63, chb = t >> 6;   // 64 face-pairs x 4 ch-groups
    const int fa2 = ft * 64 + fp;
    if (fa2 * 2 < Fn) {
      #pragma unroll
      for (int j = 0; j < 4; j++) {
        int ch = chb * 4 + j;
        u32 pv = pack2(y_s[fp * 2][ch], y_s[fp * 2 + 1][ch]);
        __builtin_nontemporal_store(pv,
            Y + ((size_t)b * 64 + seg * 16 + ch) * (Fn / 2) + fa2);
      }
    }
  } else {
    const int fl2 = t & 127, chb = t >> 7;
    if (ft * 128 + fl2 < Fn) {
      float* ob = outF + ((size_t)b * 64 + seg * 16 + chb * 8) * Fn + ft * 128 + fl2;
      #pragma unroll
      for (int j = 0; j < 8; j++) ob[(size_t)j * Fn] = y_s[fl2][chb * 8 + j];
    }
  }

  {  // stats: 16 parts x 16 channels
    const int ch = t & 15, part = t >> 4;
    float s = 0.f, s2 = 0.f;
    #pragma unroll
    for (int i = 0; i < 8; i++) {
      float v = y_s[part * 8 + i][ch];
      s += v; s2 += v * v;
    }
    rs[part][ch] = s; rs2[part][ch] = s2;
  }
  __syncthreads();
  if (t < 16) {
    float s = 0.f;
    #pragma unroll
    for (int p = 0; p < 16; p++) s += rs[p][t];
    atomicAdd(&gsum[seg * 16 + t], s);
  } else if (t < 32) {
    const int ch = t - 16;
    float s2 = 0.f;
    #pragma unroll
    for (int p = 0; p < 16; p++) s2 += rs2[p][ch];
    atomicAdd(&gsum2[seg * 16 + ch], s2);
  }
}

__global__ void k3_stats(const float* __restrict__ gsum, const float* __restrict__ gsum2,
                         const float* __restrict__ gamma, const float* __restrict__ beta,
                         float* __restrict__ ab) {
  int o = threadIdx.x;
  if (o < 64) {
    float inv = 1.0f / (float)NTOT;
    float mean = gsum[o] * inv;
    float var = gsum2[o] * inv - mean * mean;  // biased
    float r = rsqrtf(var + EPS);
    float a = gamma[o] * r;
    ab[o] = a;
    ab[64 + o] = beta[o] - mean * a;
  }
}

// k4 (bf16, k3 fused): thread = one uint2 (4 faces) -> one f32x4 store.
// Reads 512 B / writes 1 KB contiguous per wave instr; nontemporal both ways.
__global__ __launch_bounds__(256) void k4_norm_bf(
    const u32* __restrict__ Y, const float* __restrict__ gsum,
    const float* __restrict__ gsum2, const float* __restrict__ gamma,
    const float* __restrict__ beta, float* __restrict__ out) {
  int i = blockIdx.x * 256 + threadIdx.x;   // uint2 index; 3.2M total, exact cover
  int ch = (i / 12500) & 63;                // Fn/4 = 12500 uint2 per channel row
  const float inv = 1.0f / (float)NTOT;
  float mean = gsum[ch] * inv;
  float var = gsum2[ch] * inv - mean * mean;
  float a = gamma[ch] * rsqrtf(var + EPS);
  float cc = beta[ch] - mean * a;
  u32x2 u = __builtin_nontemporal_load((const u32x2*)Y + i);
  f32x4 v;
  v[0] = fmaxf(fmaf(__uint_as_float(u[0] << 16), a, cc), 0.f);
  v[1] = fmaxf(fmaf(__uint_as_float(u[0] & 0xffff0000u), a, cc), 0.f);
  v[2] = fmaxf(fmaf(__uint_as_float(u[1] << 16), a, cc), 0.f);
  v[3] = fmaxf(fmaf(__uint_as_float(u[1] & 0xffff0000u), a, cc), 0.f);
  __builtin_nontemporal_store(v, (f32x4*)out + i);
}

// k4 (fallback): in-place fp32 normalize
__global__ __launch_bounds__(256) void k4_norm_f32(float* __restrict__ out,
                                                   const float* __restrict__ ab) {
  int i = blockIdx.x * 256 + threadIdx.x;   // float4 index
  int o = (i / (Fn / 4)) & 63;
  float a = ab[o], c = ab[64 + o];
  float4 v = ((float4*)out)[i];
  v.x = fmaxf(fmaf(v.x, a, c), 0.f);
  v.y = fmaxf(fmaf(v.y, a, c), 0.f);
  v.z = fmaxf(fmaf(v.z, a, c), 0.f);
  v.w = fmaxf(fmaf(v.w, a, c), 0.f);
  ((float4*)out)[i] = v;
}

extern "C" void kernel_launch(void* const* d_in, const int* in_sizes, int n_in,
                              void* d_out, int out_size, void* d_ws, size_t ws_size,
                              hipStream_t stream) {
  const float* fea   = (const float*)d_in[0];
  const int*   ring  = (const int*)d_in[1];
  const float* W     = (const float*)d_in[2];
  const float* bias  = (const float*)d_in[3];
  const float* gamma = (const float*)d_in[4];
  const float* beta  = (const float*)d_in[5];
  float* out = (float*)d_out;

  u32* Gt = (u32*)d_ws;                                   // [B*4][Fn][8 u32] = 25.6 MB
  const size_t gtBytes = (size_t)Bn * 4 * Fn * 8 * 4;
  const size_t yBytes  = (size_t)Bn * 64 * (Fn / 2) * 4;  // 25.6 MB
  const bool bf16y = ws_size >= gtBytes + yBytes + 1024;

  u32* Y = (u32*)((char*)d_ws + gtBytes);
  float* gsum  = bf16y ? (float*)((char*)d_ws + gtBytes + yBytes)
                       : (float*)((char*)d_ws + gtBytes);
  float* gsum2 = gsum + 64;
  float* ab    = gsum + 128;

  // k1 zeroes gsum[0..127] -> no memset dispatch
  k1_mfma<<<dim3((Fn + 127) / 128, Bn), 256, 0, stream>>>(fea, W, Gt, gsum);
  const int ftiles = (Fn + 127) / 128;                    // 391
  if (bf16y) {
    k2_gather<1><<<dim3(ftiles * 16), 256, 0, stream>>>(Gt, ring, bias, Y, out, gsum, gsum2);
    k4_norm_bf<<<dim3(Bn * 64 * 12500 / 256), 256, 0, stream>>>(Y, gsum, gsum2, gamma, beta, out);
  } else {
    k2_gather<0><<<dim3(ftiles * 16), 256, 0, stream>>>(Gt, ring, bias, Y, out, gsum, gsum2);
    k3_stats<<<1, 64, 0, stream>>>(gsum, gsum2, gamma, beta, ab);
    k4_norm_f32<<<dim3((Bn * Cn * Fn / 4) / 256), 256, 0, stream>>>(out, ab);
  }
}

// Round 7
// 189.579 us; speedup vs baseline: 1.7067x; 1.0787x over previous
//
#include <hip/hip_runtime.h>
#include <hip/hip_bf16.h>
#include <stdint.h>

#define Bn 4
#define Cn 64
#define Fn 50000
#define Kn 16
#define NTOT (Bn*Fn)
#define EPS 1e-5f

typedef unsigned short u16;
typedef unsigned int u32;
typedef __attribute__((ext_vector_type(8))) short short8;
typedef __attribute__((ext_vector_type(4))) float f32x4;

__device__ __forceinline__ u16 f2bf(float x) {
  __hip_bfloat16 h = __float2bfloat16(x);
  return *reinterpret_cast<u16*>(&h);
}
__device__ __forceinline__ u32 pack2(float a, float b) {
  return (u32)f2bf(a) | ((u32)f2bf(b) << 16);
}
// async global->LDS, 16 B/lane; LDS dest = wave-uniform base + lane*16
__device__ __forceinline__ void gload_lds16(const float* g, float* l) {
  __builtin_amdgcn_global_load_lds(
      (const __attribute__((address_space(1))) u32*)(g),
      (__attribute__((address_space(3))) u32*)(l), 16, 0, 0);
}

// K1 (MFMA): Gt[(b*4+seg)][face][16ch] bf16 (32 B rows) = W x fea[b].
// 128-f tile. fea staged via global_load_lds width=16 (async DMA, no VGPR
// round-trip) into linear LDS [64ch][128f] fp32; SOURCE face-block is
// pre-swizzled by channel-octet so frag reads (fixed face, varying ch) are
// <=2-way bank aliased = free (m136/m173). MFMA layouts (m89-verified).
// Epilogue: direct uint2 stores, 512 B contiguous per instr.
// Also zeroes gsum (block 0,0) -> no separate memset dispatch.
__global__ __launch_bounds__(256) void k1_mfma(
    const float* __restrict__ fea, const float* __restrict__ W,
    u32* __restrict__ Gt, float* __restrict__ gsum) {
  const int b = blockIdx.y;
  const int f0 = blockIdx.x * 128;
  const int t = threadIdx.x;
  const int l = t & 63;
  const int quad = l >> 4;
  const int lane15 = l & 15;
  const int wv = t >> 6;
  __shared__ float a_s[64 * 128];   // 32 KB linear -> 5 blocks/CU

  if (blockIdx.x == 0 && b == 0 && t < 128) gsum[t] = 0.f;

  // Stage first (async DMA overlaps the A-frag build below).
  // Wave w stages channels 16w..16w+15: 8 issues x (2 ch: lane<32 / lane>=32).
  {
    const float* fb = fea + (size_t)b * Cn * Fn;
    #pragma unroll
    for (int i = 0; i < 8; i++) {
      const int ch = wv * 16 + 2 * i + (l >> 5);
      const int fblk = (l & 31) ^ ((((ch >> 3) & 3)) << 1);  // pre-swizzled src
      int fg = f0 + fblk * 4;
      if (fg >= Fn) fg = f0;        // clamp: garbage faces never consumed
      gload_lds16(fb + (size_t)ch * Fn + fg, &a_s[(wv * 16 + 2 * i) * 128]);
    }
  }

  // A-frags: o = ot*16 + lane15, c = kk*32 + quad*8 + j  (W 64x64, cache-hot)
  short8 afr[4][2];
  #pragma unroll
  for (int ot = 0; ot < 4; ot++) {
    #pragma unroll
    for (int kk = 0; kk < 2; kk++) {
      const float* wr = W + (ot * 16 + lane15) * 64 + kk * 32 + quad * 8;
      float4 wa = *(const float4*)wr;
      float4 wb = *(const float4*)(wr + 4);
      union { short8 v; u32 u[4]; } fr;
      fr.u[0] = pack2(wa.x, wa.y); fr.u[1] = pack2(wa.z, wa.w);
      fr.u[2] = pack2(wb.x, wb.y); fr.u[3] = pack2(wb.z, wb.w);
      afr[ot][kk] = fr.v;
    }
  }
  __syncthreads();   // drains the global_load_lds queue before first ds_read

  f32x4 acc[4][2];
  #pragma unroll
  for (int ot = 0; ot < 4; ot++)
    #pragma unroll
    for (int ft = 0; ft < 2; ft++) acc[ot][ft] = (f32x4){0.f, 0.f, 0.f, 0.f};

  #pragma unroll
  for (int ft = 0; ft < 2; ft++) {
    const int fl = wv * 32 + ft * 16 + lane15;
    const int fsw = fl ^ (quad << 3);       // read-side swizzle: ch-octet = quad
    float x[16];
    #pragma unroll
    for (int j = 0; j < 8; j++) x[j] = a_s[(quad * 8 + j) * 128 + fsw];
    #pragma unroll
    for (int j = 0; j < 8; j++) x[8 + j] = a_s[(32 + quad * 8 + j) * 128 + fsw];
    union { short8 s; u32 u[4]; } b0, b1;
    #pragma unroll
    for (int p = 0; p < 4; p++) {
      b0.u[p] = pack2(x[2 * p], x[2 * p + 1]);
      b1.u[p] = pack2(x[8 + 2 * p], x[8 + 2 * p + 1]);
    }
    #pragma unroll
    for (int ot = 0; ot < 4; ot++) {
      acc[ot][ft] = __builtin_amdgcn_mfma_f32_16x16x32_bf16(afr[ot][0], b0.s, acc[ot][ft], 0, 0, 0);
      acc[ot][ft] = __builtin_amdgcn_mfma_f32_16x16x32_bf16(afr[ot][1], b1.s, acc[ot][ft], 0, 0, 0);
    }
  }

  // Epilogue: o = ot*16 + quad*4 + r -> seg = ot; uint2 at u32-offset quad*2.
  // Per (ot,ft) instruction: 64 lanes cover 16 faces x 32 B = 512 B contiguous.
  #pragma unroll
  for (int ot = 0; ot < 4; ot++) {
    #pragma unroll
    for (int ft = 0; ft < 2; ft++) {
      int fg = f0 + wv * 32 + ft * 16 + lane15;
      if (fg < Fn) {
        uint2 pv;
        pv.x = pack2(acc[ot][ft][0], acc[ot][ft][1]);
        pv.y = pack2(acc[ot][ft][2], acc[ot][ft][3]);
        *(uint2*)(Gt + ((size_t)(b * 4 + ot) * Fn + fg) * 8 + quad * 2) = pv;
      }
    }
  }
}

// K2: byte-identical to round-0 (best measured: 67 us; NT hints proven -14%).
// block = (b,seg) x 128 faces, 32 B rows, 2 lanes/row.
template<int WRITE_BF16>
__global__ __launch_bounds__(256) void k2_gather(
    const u32* __restrict__ Gt, const int* __restrict__ ring,
    const float* __restrict__ bias, u32* __restrict__ Y, float* __restrict__ outF,
    float* __restrict__ gsum, float* __restrict__ gsum2) {
  const int bid = blockIdx.x;
  const int combo = bid & 15;
  const int ft = bid >> 4;
  const int b = combo >> 2;
  const int seg = combo & 3;
  const int t = threadIdx.x;
  const int face_l = t >> 1;          // 0..127
  const int half = t & 1;
  const int fa = ft * 128 + face_l;
  const bool valid = fa < Fn;

  __shared__ float y_s[128][17];
  __shared__ float rs[16][17];
  __shared__ float rs2[16][17];

  float acc[8];
  #pragma unroll
  for (int i = 0; i < 8; i++) acc[i] = 0.f;

  const int c0 = seg * 16 + half * 8;
  float bv[8];
  #pragma unroll
  for (int i = 0; i < 8; i++) bv[i] = bias[c0 + i];

  if (valid) {
    const int4* rp = (const int4*)(ring + ((size_t)b * Fn + fa) * Kn);
    int4 i0 = rp[0], i1 = rp[1], i2 = rp[2], i3 = rp[3];
    int idx[16] = {i0.x,i0.y,i0.z,i0.w, i1.x,i1.y,i1.z,i1.w,
                   i2.x,i2.y,i2.z,i2.w, i3.x,i3.y,i3.z,i3.w};
    const uint4* Gs = (const uint4*)(Gt + (size_t)combo * Fn * 8);
    uint4 v[8], w[8];
    #pragma unroll
    for (int k = 0; k < 8; k++) v[k] = Gs[(size_t)idx[k] * 2 + half];
    #pragma unroll
    for (int k = 0; k < 8; k++) w[k] = Gs[(size_t)idx[8 + k] * 2 + half];
    #pragma unroll
    for (int k = 0; k < 8; k++) {
      u32 uu[4] = {v[k].x, v[k].y, v[k].z, v[k].w};
      #pragma unroll
      for (int p = 0; p < 4; p++) {
        acc[2*p]   += __uint_as_float(uu[p] << 16);
        acc[2*p+1] += __uint_as_float(uu[p] & 0xffff0000u);
      }
    }
    #pragma unroll
    for (int k = 0; k < 8; k++) {
      u32 uu[4] = {w[k].x, w[k].y, w[k].z, w[k].w};
      #pragma unroll
      for (int p = 0; p < 4; p++) {
        acc[2*p]   += __uint_as_float(uu[p] << 16);
        acc[2*p+1] += __uint_as_float(uu[p] & 0xffff0000u);
      }
    }
  }
  #pragma unroll
  for (int i = 0; i < 8; i++) acc[i] = valid ? acc[i] + bv[i] : 0.f;
  #pragma unroll
  for (int i = 0; i < 8; i++) y_s[face_l][half * 8 + i] = acc[i];
  __syncthreads();

  if (WRITE_BF16) {
    const int fp = t & 63, chb = t >> 6;   // 64 face-pairs x 4 ch-groups
    const int fa2 = ft * 64 + fp;
    if (fa2 * 2 < Fn) {
      #pragma unroll
      for (int j = 0; j < 4; j++) {
        int ch = chb * 4 + j;
        Y[((size_t)b * 64 + seg * 16 + ch) * (Fn / 2) + fa2] =
            pack2(y_s[fp * 2][ch], y_s[fp * 2 + 1][ch]);
      }
    }
  } else {
    const int fl2 = t & 127, chb = t >> 7;
    if (ft * 128 + fl2 < Fn) {
      float* ob = outF + ((size_t)b * 64 + seg * 16 + chb * 8) * Fn + ft * 128 + fl2;
      #pragma unroll
      for (int j = 0; j < 8; j++) ob[(size_t)j * Fn] = y_s[fl2][chb * 8 + j];
    }
  }

  {  // stats: 16 parts x 16 channels
    const int ch = t & 15, part = t >> 4;
    float s = 0.f, s2 = 0.f;
    #pragma unroll
    for (int i = 0; i < 8; i++) {
      float v = y_s[part * 8 + i][ch];
      s += v; s2 += v * v;
    }
    rs[part][ch] = s; rs2[part][ch] = s2;
  }
  __syncthreads();
  if (t < 16) {
    float s = 0.f;
    #pragma unroll
    for (int p = 0; p < 16; p++) s += rs[p][t];
    atomicAdd(&gsum[seg * 16 + t], s);
  } else if (t < 32) {
    const int ch = t - 16;
    float s2 = 0.f;
    #pragma unroll
    for (int p = 0; p < 16; p++) s2 += rs2[p][ch];
    atomicAdd(&gsum2[seg * 16 + ch], s2);
  }
}

__global__ void k3_stats(const float* __restrict__ gsum, const float* __restrict__ gsum2,
                         const float* __restrict__ gamma, const float* __restrict__ beta,
                         float* __restrict__ ab) {
  int o = threadIdx.x;
  if (o < 64) {
    float inv = 1.0f / (float)NTOT;
    float mean = gsum[o] * inv;
    float var = gsum2[o] * inv - mean * mean;  // biased
    float r = rsqrtf(var + EPS);
    float a = gamma[o] * r;
    ab[o] = a;
    ab[64 + o] = beta[o] - mean * a;
  }
}

// k4 (bf16, k3 fused): thread = one uint2 (4 faces) -> one float4 store.
// Reads 512 B / writes 1 KB contiguous per wave instr (fully coalesced).
__global__ __launch_bounds__(256) void k4_norm_bf(
    const u32* __restrict__ Y, const float* __restrict__ gsum,
    const float* __restrict__ gsum2, const float* __restrict__ gamma,
    const float* __restrict__ beta, float* __restrict__ out) {
  int i = blockIdx.x * 256 + threadIdx.x;   // uint2 index; 3.2M total, exact cover
  int ch = (i / 12500) & 63;                // Fn/4 = 12500 uint2 per channel row
  const float inv = 1.0f / (float)NTOT;
  float mean = gsum[ch] * inv;
  float var = gsum2[ch] * inv - mean * mean;
  float a = gamma[ch] * rsqrtf(var + EPS);
  float cc = beta[ch] - mean * a;
  uint2 u = ((const uint2*)Y)[i];
  float4 v;
  v.x = fmaxf(fmaf(__uint_as_float(u.x << 16), a, cc), 0.f);
  v.y = fmaxf(fmaf(__uint_as_float(u.x & 0xffff0000u), a, cc), 0.f);
  v.z = fmaxf(fmaf(__uint_as_float(u.y << 16), a, cc), 0.f);
  v.w = fmaxf(fmaf(__uint_as_float(u.y & 0xffff0000u), a, cc), 0.f);
  ((float4*)out)[i] = v;
}

// k4 (fallback): in-place fp32 normalize
__global__ __launch_bounds__(256) void k4_norm_f32(float* __restrict__ out,
                                                   const float* __restrict__ ab) {
  int i = blockIdx.x * 256 + threadIdx.x;   // float4 index
  int o = (i / (Fn / 4)) & 63;
  float a = ab[o], c = ab[64 + o];
  float4 v = ((float4*)out)[i];
  v.x = fmaxf(fmaf(v.x, a, c), 0.f);
  v.y = fmaxf(fmaf(v.y, a, c), 0.f);
  v.z = fmaxf(fmaf(v.z, a, c), 0.f);
  v.w = fmaxf(fmaf(v.w, a, c), 0.f);
  ((float4*)out)[i] = v;
}

extern "C" void kernel_launch(void* const* d_in, const int* in_sizes, int n_in,
                              void* d_out, int out_size, void* d_ws, size_t ws_size,
                              hipStream_t stream) {
  const float* fea   = (const float*)d_in[0];
  const int*   ring  = (const int*)d_in[1];
  const float* W     = (const float*)d_in[2];
  const float* bias  = (const float*)d_in[3];
  const float* gamma = (const float*)d_in[4];
  const float* beta  = (const float*)d_in[5];
  float* out = (float*)d_out;

  u32* Gt = (u32*)d_ws;                                   // [B*4][Fn][8 u32] = 25.6 MB
  const size_t gtBytes = (size_t)Bn * 4 * Fn * 8 * 4;
  const size_t yBytes  = (size_t)Bn * 64 * (Fn / 2) * 4;  // 25.6 MB
  const bool bf16y = ws_size >= gtBytes + yBytes + 1024;

  u32* Y = (u32*)((char*)d_ws + gtBytes);
  float* gsum  = bf16y ? (float*)((char*)d_ws + gtBytes + yBytes)
                       : (float*)((char*)d_ws + gtBytes);
  float* gsum2 = gsum + 64;
  float* ab    = gsum + 128;

  // k1 zeroes gsum[0..127] -> no memset dispatch
  k1_mfma<<<dim3((Fn + 127) / 128, Bn), 256, 0, stream>>>(fea, W, Gt, gsum);
  const int ftiles = (Fn + 127) / 128;                    // 391
  if (bf16y) {
    k2_gather<1><<<dim3(ftiles * 16), 256, 0, stream>>>(Gt, ring, bias, Y, out, gsum, gsum2);
    k4_norm_bf<<<dim3(Bn * 64 * 12500 / 256), 256, 0, stream>>>(Y, gsum, gsum2, gamma, beta, out);
  } else {
    k2_gather<0><<<dim3(ftiles * 16), 256, 0, stream>>>(Gt, ring, bias, Y, out, gsum, gsum2);
    k3_stats<<<1, 64, 0, stream>>>(gsum, gsum2, gamma, beta, ab);
    k4_norm_f32<<<dim3((Bn * Cn * Fn / 4) / 256), 256, 0, stream>>>(out, ab);
  }
}